// Round 14
// baseline (84.641 us; speedup 1.0000x reference)
//
#include <hip/hip_runtime.h>
#include <hip/hip_bf16.h>
#include <math.h>

#define NB 1024
#define N 256
#define EPS 1e-6f
#define SQRT_EPS 1e-3f   // sqrt(1e-6)

typedef short bf16x8 __attribute__((ext_vector_type(8)));
typedef float f32x4  __attribute__((ext_vector_type(4)));

__device__ __forceinline__ float fast_rcp(float x) {
    return __builtin_amdgcn_rcpf(x);
}
__device__ __forceinline__ float sigmoidf(float x) {
    return fast_rcp(1.0f + __expf(-x));
}
__device__ __forceinline__ float fast_tanh(float x) {
    float ax = fabsf(x);
    float e  = __expf(2.0f * ax);
    float t  = 1.0f - 2.0f * fast_rcp(e + 1.0f);
    return copysignf(t, x);
}
__device__ __forceinline__ unsigned short to_bf16(float f) {
    __hip_bfloat16 h = __float2bfloat16(f);
    return *(unsigned short*)&h;
}

// ---- prep: convert 6 weight mats (6x65536 f32) to bf16 ----
__global__ __launch_bounds__(256) void prep_kernel(
    const float* __restrict__ Wd1, const float* __restrict__ Wu1,
    const float* __restrict__ Wm1, const float* __restrict__ Wd2,
    const float* __restrict__ Wu2, const float* __restrict__ Wm2,
    unsigned short* __restrict__ out)
{
    const int fi = blockIdx.x * 256 + threadIdx.x;   // float4 idx; 98304 total
    const int r  = fi >> 14;                          // matrix 0..5
    const int off = (fi & 16383) * 4;
    const float* src = (r == 0) ? Wd1 : (r == 1) ? Wu1 : (r == 2) ? Wm1
                     : (r == 3) ? Wd2 : (r == 4) ? Wu2 : Wm2;
    float4 f = *(const float4*)(src + off);
    ushort4 o;
    o.x = to_bf16(f.x); o.y = to_bf16(f.y); o.z = to_bf16(f.z); o.w = to_bf16(f.w);
    *(ushort4*)(out + r * 65536 + off) = o;
}

// ---- fused MLP: 64 blocks x 1024 threads (16 waves = 4 waves/SIMD).
// Block = 16 batch rows. Wave w owns n-tile [w*16, w*16+16) for both layers
// and all 3 MLPs (8 MFMAs per tile per mlp). h1 (bf16) and h2 (f32) live in
// LDS only. Epilogue: wave w = batch row w, butterfly all-reduce.
// mfma_f32_16x16x32_bf16 frags (verified R12, absmax 0.031):
//   A/B: lane idx = lane&15 (row of A / col of B), k = (lane>>4)*8 + e
//   C/D: col = lane&15 (neuron), row = (lane>>4)*4 + reg (batch row)
#define H1S 264
__global__ __launch_bounds__(1024) void mlp_fused_kernel(
    const float* __restrict__ x, const unsigned short* __restrict__ Wb,
    const float* __restrict__ bd1, const float* __restrict__ bu1,
    const float* __restrict__ bm1, const float* __restrict__ bd2,
    const float* __restrict__ bu2, const float* __restrict__ bm2,
    const float* __restrict__ v,
    float* __restrict__ out_mean, float* __restrict__ out_z,
    float* __restrict__ ws_a, float* __restrict__ ws_tp, float* __restrict__ ws_s)
{
    __shared__ unsigned short h1s[3][16][H1S];   // 25.3 KB bf16
    __shared__ float h2f[3][16][H1S];            // 50.7 KB f32

    const int tid = threadIdx.x;
    const int w   = tid >> 6;          // wave 0..15 = n-tile
    const int l   = tid & 63;
    const int ml  = l & 15;
    const int kg  = l >> 4;
    const int b0  = blockIdx.x * 16;
    const int n0  = w * 16;

    // ---- layer 1: A-frags from x (f32 -> bf16 in-flight) ----
    bf16x8 af[8];
    {
        const float* xrow = x + (size_t)(b0 + ml) * N;
        #pragma unroll
        for (int kq = 0; kq < 8; ++kq) {
            float4 f0 = *(const float4*)(xrow + kq * 32 + kg * 8);
            float4 f1 = *(const float4*)(xrow + kq * 32 + kg * 8 + 4);
            bf16x8 a;
            a[0] = (short)to_bf16(f0.x); a[1] = (short)to_bf16(f0.y);
            a[2] = (short)to_bf16(f0.z); a[3] = (short)to_bf16(f0.w);
            a[4] = (short)to_bf16(f1.x); a[5] = (short)to_bf16(f1.y);
            a[6] = (short)to_bf16(f1.z); a[7] = (short)to_bf16(f1.w);
            af[kq] = a;
        }
    }
    #pragma unroll
    for (int mlp = 0; mlp < 3; ++mlp) {
        const unsigned short* Wl = Wb + (size_t)mlp * 65536;
        f32x4 acc = {0.f, 0.f, 0.f, 0.f};
        #pragma unroll
        for (int kq = 0; kq < 8; ++kq) {
            bf16x8 bf = *(const bf16x8*)(Wl + (size_t)(n0 + ml) * N + kq * 32 + kg * 8);
            acc = __builtin_amdgcn_mfma_f32_16x16x32_bf16(af[kq], bf, acc, 0, 0, 0);
        }
        const float* bias = (mlp == 0) ? bd1 : (mlp == 1) ? bu1 : bm1;
        const int n = n0 + ml;
        const float bb = bias[n];
        #pragma unroll
        for (int reg = 0; reg < 4; ++reg) {
            const int row = kg * 4 + reg;
            float val = acc[reg] + bb;
            float act = (mlp < 2) ? sigmoidf(val) : fast_tanh(val);
            h1s[mlp][row][n] = to_bf16(act);
        }
    }
    __syncthreads();

    // ---- layer 2: A-frags from h1s (LDS bf16) ----
    #pragma unroll
    for (int mlp = 0; mlp < 3; ++mlp) {
        bf16x8 af2[8];
        #pragma unroll
        for (int kq = 0; kq < 8; ++kq)
            af2[kq] = *(const bf16x8*)&h1s[mlp][ml][kq * 32 + kg * 8];
        const unsigned short* Wl = Wb + (size_t)(3 + mlp) * 65536;
        f32x4 acc = {0.f, 0.f, 0.f, 0.f};
        #pragma unroll
        for (int kq = 0; kq < 8; ++kq) {
            bf16x8 bf = *(const bf16x8*)(Wl + (size_t)(n0 + ml) * N + kq * 32 + kg * 8);
            acc = __builtin_amdgcn_mfma_f32_16x16x32_bf16(af2[kq], bf, acc, 0, 0, 0);
        }
        const float* bias = (mlp == 0) ? bd2 : (mlp == 1) ? bu2 : bm2;
        const int n = n0 + ml;
        const float bb = bias[n];
        #pragma unroll
        for (int reg = 0; reg < 4; ++reg) {
            const int row = kg * 4 + reg;
            float val = acc[reg] + bb;
            float act = (mlp < 2) ? sigmoidf(val) : fast_tanh(val);
            h2f[mlp][row][n] = act;              // d,u,m f32
        }
    }
    __syncthreads();

    // ---- epilogue: wave w = batch row w ----
    {
        const int r = w;
        float dd[4], uu[4], vv[4];
        float Su = 0.f, qs = 0.f, Sv = 0.f;
        #pragma unroll
        for (int c = 0; c < 4; ++c) {
            const int n = l + 64 * c;
            dd[c] = h2f[0][r][n];
            uu[c] = h2f[1][r][n];
            vv[c] = v[(size_t)(b0 + r) * N + n];
            Su += uu[c];
            qs += uu[c] * uu[c] * fast_rcp(dd[c]);
            Sv += vv[c];
        }
        #pragma unroll
        for (int off = 1; off < 64; off <<= 1) {
            Su += __shfl_xor(Su, off, 64);
            qs += __shfl_xor(qs, off, 64);
            Sv += __shfl_xor(Sv, off, 64);
        }
        const float utDu  = qs + EPS * Su * Su;
        const float sqeta = rsqrtf(1.0f + utDu);
        const float right = (1.0f - sqeta) / utDu;

        float aC[4], tpC[4], sC[4];
        float sv = 0.f;
        #pragma unroll
        for (int c = 0; c < 4; ++c) {
            const float inv_d = fast_rcp(dd[c]);
            aC[c]  = sqrtf(inv_d + EPS);
            sC[c]  = uu[c] * aC[c] + SQRT_EPS * (Su - uu[c]);
            tpC[c] = right * (uu[c] * inv_d + EPS * Su);
            sv += sC[c] * vv[c];
        }
        #pragma unroll
        for (int off = 1; off < 64; off <<= 1)
            sv += __shfl_xor(sv, off, 64);

        #pragma unroll
        for (int c = 0; c < 4; ++c) {
            const int n = l + 64 * c;
            const size_t idx = (size_t)(b0 + r) * N + n;
            const float m_ = h2f[2][r][n];
            out_mean[idx] = m_;
            out_z[idx]    = SQRT_EPS * Sv + (aC[c] - SQRT_EPS) * vv[c] - tpC[c] * sv + m_;
            ws_a[idx]     = aC[c];
            ws_tp[idx]    = tpC[c];
            ws_s[idx]     = sC[c];
        }
    }
}

// r_R4 (BYTE-IDENTICAL: ~38.9 us / 6.9 TB/s — at write roofline).
__global__ __launch_bounds__(256) void r_kernel(
    const float* __restrict__ ws_a, const float* __restrict__ ws_tp,
    const float* __restrict__ ws_s, float* __restrict__ R)
{
    __shared__ float s_lds[N];
    __shared__ float a_lds[64];
    __shared__ float tp_lds[64];

    const int tid   = threadIdx.x;
    const int b     = blockIdx.x >> 2;
    const int chunk = blockIdx.x & 3;
    const int ibase = chunk * 64;

    s_lds[tid] = ws_s[(size_t)b * N + tid];
    if (tid < 64) {
        a_lds[tid]  = ws_a[(size_t)b * N + ibase + tid];
        tp_lds[tid] = ws_tp[(size_t)b * N + ibase + tid];
    }
    __syncthreads();

    const int j4 = tid & 63;
    const int il = tid >> 6;
    const float4 sv = ((const float4*)s_lds)[j4];
    float4* Rb = (float4*)(R + (size_t)b * N * N);
    const int jb = j4 * 4;

    #pragma unroll
    for (int it = 0; it < 16; ++it) {
        const int i_loc = it * 4 + il;
        const int i     = ibase + i_loc;
        const float a   = a_lds[i_loc];
        const float tp  = tp_lds[i_loc];
        float4 o;
        o.x = SQRT_EPS - tp * sv.x;
        o.y = SQRT_EPS - tp * sv.y;
        o.z = SQRT_EPS - tp * sv.z;
        o.w = SQRT_EPS - tp * sv.w;
        if (i >= jb && i < jb + 4) {
            const float add = a - SQRT_EPS;
            if      (i == jb)     o.x += add;
            else if (i == jb + 1) o.y += add;
            else if (i == jb + 2) o.z += add;
            else                  o.w += add;
        }
        Rb[(size_t)i * 64 + j4] = o;
    }
}

extern "C" void kernel_launch(void* const* d_in, const int* in_sizes, int n_in,
                              void* d_out, int out_size, void* d_ws, size_t ws_size,
                              hipStream_t stream) {
    const float* x   = (const float*)d_in[0];
    const float* Wd1 = (const float*)d_in[1];
    const float* bd1 = (const float*)d_in[2];
    const float* Wd2 = (const float*)d_in[3];
    const float* bd2 = (const float*)d_in[4];
    const float* Wu1 = (const float*)d_in[5];
    const float* bu1 = (const float*)d_in[6];
    const float* Wu2 = (const float*)d_in[7];
    const float* bu2 = (const float*)d_in[8];
    const float* Wm1 = (const float*)d_in[9];
    const float* bm1 = (const float*)d_in[10];
    const float* Wm2 = (const float*)d_in[11];
    const float* bm2 = (const float*)d_in[12];
    const float* v   = (const float*)d_in[13];

    float* out      = (float*)d_out;
    float* out_mean = out;                                   // [1024,256]
    float* R        = out + (size_t)NB * N;                  // [1024,256,256]
    float* out_z    = R + (size_t)NB * N * N;                // [1024,256]

    float* wsf   = (float*)d_ws;
    float* ws_a  = wsf;                            // [1024,256] f32
    float* ws_tp = wsf + (size_t)NB * N;
    float* ws_s  = wsf + (size_t)2 * NB * N;
    unsigned short* Wb = (unsigned short*)(wsf + (size_t)3 * NB * N);  // 6x65536 bf16

    prep_kernel<<<384, 256, 0, stream>>>(Wd1, Wu1, Wm1, Wd2, Wu2, Wm2, Wb);

    mlp_fused_kernel<<<NB / 16, 1024, 0, stream>>>(
        x, Wb, bd1, bu1, bm1, bd2, bu2, bm2, v,
        out_mean, out_z, ws_a, ws_tp, ws_s);

    r_kernel<<<NB * 4, 256, 0, stream>>>(ws_a, ws_tp, ws_s, R);
}

// Round 15
// 84.518 us; speedup vs baseline: 1.0015x; 1.0015x over previous
//
#include <hip/hip_runtime.h>
#include <hip/hip_bf16.h>
#include <math.h>

#define NB 1024
#define N 256
#define EPS 1e-6f
#define SQRT_EPS 1e-3f   // sqrt(1e-6)

typedef short bf16x8 __attribute__((ext_vector_type(8)));
typedef float f32x4  __attribute__((ext_vector_type(4)));

__device__ __forceinline__ float fast_rcp(float x) {
    return __builtin_amdgcn_rcpf(x);
}
__device__ __forceinline__ float sigmoidf(float x) {
    return fast_rcp(1.0f + __expf(-x));
}
__device__ __forceinline__ float fast_tanh(float x) {
    float ax = fabsf(x);
    float e  = __expf(2.0f * ax);
    float t  = 1.0f - 2.0f * fast_rcp(e + 1.0f);
    return copysignf(t, x);
}
__device__ __forceinline__ unsigned short to_bf16(float f) {
    __hip_bfloat16 h = __float2bfloat16(f);
    return *(unsigned short*)&h;
}

// ---- prep: convert 6 weight mats (6x65536 f32) to bf16 ----
__global__ __launch_bounds__(256) void prep_kernel(
    const float* __restrict__ Wd1, const float* __restrict__ Wu1,
    const float* __restrict__ Wm1, const float* __restrict__ Wd2,
    const float* __restrict__ Wu2, const float* __restrict__ Wm2,
    unsigned short* __restrict__ out)
{
    const int fi = blockIdx.x * 256 + threadIdx.x;   // float4 idx; 98304 total
    const int r  = fi >> 14;                          // matrix 0..5
    const int off = (fi & 16383) * 4;
    const float* src = (r == 0) ? Wd1 : (r == 1) ? Wu1 : (r == 2) ? Wm1
                     : (r == 3) ? Wd2 : (r == 4) ? Wu2 : Wm2;
    float4 f = *(const float4*)(src + off);
    ushort4 o;
    o.x = to_bf16(f.x); o.y = to_bf16(f.y); o.z = to_bf16(f.z); o.w = to_bf16(f.w);
    *(ushort4*)(out + r * 65536 + off) = o;
}

// ---- fused MLP, full-GPU: 256 blocks x 1024 threads (16 waves/block).
// Block = 4 batch rows (A-frag 16 rows = the 4 real rows replicated x4;
// only kg==0 lanes write C rows 0..3). Wave w owns n-tile [w*16, w*16+16).
// h1 (bf16) and h2 (f32) in LDS. Epilogue: waves 0-3 = rows 0-3.
// mfma_f32_16x16x32_bf16 frags (verified R12-R14, absmax 0.031):
//   A/B: lane idx = lane&15, k = (lane>>4)*8 + e
//   C/D: col = lane&15 (neuron), row = (lane>>4)*4 + reg (batch row)
#define H1S 264
__global__ __launch_bounds__(1024) void mlp_fused256_kernel(
    const float* __restrict__ x, const unsigned short* __restrict__ Wb,
    const float* __restrict__ bd1, const float* __restrict__ bu1,
    const float* __restrict__ bm1, const float* __restrict__ bd2,
    const float* __restrict__ bu2, const float* __restrict__ bm2,
    const float* __restrict__ v,
    float* __restrict__ out_mean, float* __restrict__ out_z,
    float* __restrict__ ws_a, float* __restrict__ ws_tp, float* __restrict__ ws_s)
{
    __shared__ unsigned short h1s[3][4][H1S];   // 6.3 KB bf16
    __shared__ float h2f[3][4][H1S];            // 12.7 KB f32

    const int tid = threadIdx.x;
    const int w   = tid >> 6;          // wave 0..15 = n-tile
    const int l   = tid & 63;
    const int ml  = l & 15;
    const int kg  = l >> 4;
    const int b0  = blockIdx.x * 4;
    const int n0  = w * 16;
    const int n   = n0 + ml;

    // ---- layer 1: A-frags from x rows b0+(ml&3), f32->bf16 in-flight ----
    bf16x8 af[8];
    {
        const float* xrow = x + (size_t)(b0 + (ml & 3)) * N;
        #pragma unroll
        for (int kq = 0; kq < 8; ++kq) {
            float4 f0 = *(const float4*)(xrow + kq * 32 + kg * 8);
            float4 f1 = *(const float4*)(xrow + kq * 32 + kg * 8 + 4);
            bf16x8 a;
            a[0] = (short)to_bf16(f0.x); a[1] = (short)to_bf16(f0.y);
            a[2] = (short)to_bf16(f0.z); a[3] = (short)to_bf16(f0.w);
            a[4] = (short)to_bf16(f1.x); a[5] = (short)to_bf16(f1.y);
            a[6] = (short)to_bf16(f1.z); a[7] = (short)to_bf16(f1.w);
            af[kq] = a;
        }
    }
    #pragma unroll
    for (int mlp = 0; mlp < 3; ++mlp) {
        const unsigned short* Wl = Wb + (size_t)mlp * 65536;
        f32x4 acc = {0.f, 0.f, 0.f, 0.f};
        #pragma unroll
        for (int kq = 0; kq < 8; ++kq) {
            bf16x8 bf = *(const bf16x8*)(Wl + (size_t)n * N + kq * 32 + kg * 8);
            acc = __builtin_amdgcn_mfma_f32_16x16x32_bf16(af[kq], bf, acc, 0, 0, 0);
        }
        if (kg == 0) {                      // rows 0..3 = the 4 real rows
            const float* bias = (mlp == 0) ? bd1 : (mlp == 1) ? bu1 : bm1;
            const float bb = bias[n];
            #pragma unroll
            for (int reg = 0; reg < 4; ++reg) {
                float val = acc[reg] + bb;
                float act = (mlp < 2) ? sigmoidf(val) : fast_tanh(val);
                h1s[mlp][reg][n] = to_bf16(act);
            }
        }
    }
    __syncthreads();

    // ---- layer 2: A-frags from h1s row (ml&3) (LDS broadcast reads) ----
    #pragma unroll
    for (int mlp = 0; mlp < 3; ++mlp) {
        bf16x8 af2[8];
        #pragma unroll
        for (int kq = 0; kq < 8; ++kq)
            af2[kq] = *(const bf16x8*)&h1s[mlp][ml & 3][kq * 32 + kg * 8];
        const unsigned short* Wl = Wb + (size_t)(3 + mlp) * 65536;
        f32x4 acc = {0.f, 0.f, 0.f, 0.f};
        #pragma unroll
        for (int kq = 0; kq < 8; ++kq) {
            bf16x8 bf = *(const bf16x8*)(Wl + (size_t)n * N + kq * 32 + kg * 8);
            acc = __builtin_amdgcn_mfma_f32_16x16x32_bf16(af2[kq], bf, acc, 0, 0, 0);
        }
        if (kg == 0) {
            const float* bias = (mlp == 0) ? bd2 : (mlp == 1) ? bu2 : bm2;
            const float bb = bias[n];
            #pragma unroll
            for (int reg = 0; reg < 4; ++reg) {
                float val = acc[reg] + bb;
                float act = (mlp < 2) ? sigmoidf(val) : fast_tanh(val);
                h2f[mlp][reg][n] = act;          // d,u,m f32
            }
        }
    }
    __syncthreads();

    // ---- epilogue: waves 0-3 = batch rows 0-3 ----
    if (w < 4) {
        const int r = w;
        float dd[4], uu[4], vv[4];
        float Su = 0.f, qs = 0.f, Sv = 0.f;
        #pragma unroll
        for (int c = 0; c < 4; ++c) {
            const int nn = l + 64 * c;
            dd[c] = h2f[0][r][nn];
            uu[c] = h2f[1][r][nn];
            vv[c] = v[(size_t)(b0 + r) * N + nn];
            Su += uu[c];
            qs += uu[c] * uu[c] * fast_rcp(dd[c]);
            Sv += vv[c];
        }
        #pragma unroll
        for (int off = 1; off < 64; off <<= 1) {
            Su += __shfl_xor(Su, off, 64);
            qs += __shfl_xor(qs, off, 64);
            Sv += __shfl_xor(Sv, off, 64);
        }
        const float utDu  = qs + EPS * Su * Su;
        const float sqeta = rsqrtf(1.0f + utDu);
        const float right = (1.0f - sqeta) / utDu;

        float aC[4], tpC[4], sC[4];
        float sv = 0.f;
        #pragma unroll
        for (int c = 0; c < 4; ++c) {
            const float inv_d = fast_rcp(dd[c]);
            aC[c]  = sqrtf(inv_d + EPS);
            sC[c]  = uu[c] * aC[c] + SQRT_EPS * (Su - uu[c]);
            tpC[c] = right * (uu[c] * inv_d + EPS * Su);
            sv += sC[c] * vv[c];
        }
        #pragma unroll
        for (int off = 1; off < 64; off <<= 1)
            sv += __shfl_xor(sv, off, 64);

        #pragma unroll
        for (int c = 0; c < 4; ++c) {
            const int nn = l + 64 * c;
            const size_t idx = (size_t)(b0 + r) * N + nn;
            const float m_ = h2f[2][r][nn];
            out_mean[idx] = m_;
            out_z[idx]    = SQRT_EPS * Sv + (aC[c] - SQRT_EPS) * vv[c] - tpC[c] * sv + m_;
            ws_a[idx]     = aC[c];
            ws_tp[idx]    = tpC[c];
            ws_s[idx]     = sC[c];
        }
    }
}

// r_R4 (BYTE-IDENTICAL: ~38.9 us / 6.9 TB/s — at write roofline).
__global__ __launch_bounds__(256) void r_kernel(
    const float* __restrict__ ws_a, const float* __restrict__ ws_tp,
    const float* __restrict__ ws_s, float* __restrict__ R)
{
    __shared__ float s_lds[N];
    __shared__ float a_lds[64];
    __shared__ float tp_lds[64];

    const int tid   = threadIdx.x;
    const int b     = blockIdx.x >> 2;
    const int chunk = blockIdx.x & 3;
    const int ibase = chunk * 64;

    s_lds[tid] = ws_s[(size_t)b * N + tid];
    if (tid < 64) {
        a_lds[tid]  = ws_a[(size_t)b * N + ibase + tid];
        tp_lds[tid] = ws_tp[(size_t)b * N + ibase + tid];
    }
    __syncthreads();

    const int j4 = tid & 63;
    const int il = tid >> 6;
    const float4 sv = ((const float4*)s_lds)[j4];
    float4* Rb = (float4*)(R + (size_t)b * N * N);
    const int jb = j4 * 4;

    #pragma unroll
    for (int it = 0; it < 16; ++it) {
        const int i_loc = it * 4 + il;
        const int i     = ibase + i_loc;
        const float a   = a_lds[i_loc];
        const float tp  = tp_lds[i_loc];
        float4 o;
        o.x = SQRT_EPS - tp * sv.x;
        o.y = SQRT_EPS - tp * sv.y;
        o.z = SQRT_EPS - tp * sv.z;
        o.w = SQRT_EPS - tp * sv.w;
        if (i >= jb && i < jb + 4) {
            const float add = a - SQRT_EPS;
            if      (i == jb)     o.x += add;
            else if (i == jb + 1) o.y += add;
            else if (i == jb + 2) o.z += add;
            else                  o.w += add;
        }
        Rb[(size_t)i * 64 + j4] = o;
    }
}

extern "C" void kernel_launch(void* const* d_in, const int* in_sizes, int n_in,
                              void* d_out, int out_size, void* d_ws, size_t ws_size,
                              hipStream_t stream) {
    const float* x   = (const float*)d_in[0];
    const float* Wd1 = (const float*)d_in[1];
    const float* bd1 = (const float*)d_in[2];
    const float* Wd2 = (const float*)d_in[3];
    const float* bd2 = (const float*)d_in[4];
    const float* Wu1 = (const float*)d_in[5];
    const float* bu1 = (const float*)d_in[6];
    const float* Wu2 = (const float*)d_in[7];
    const float* bu2 = (const float*)d_in[8];
    const float* Wm1 = (const float*)d_in[9];
    const float* bm1 = (const float*)d_in[10];
    const float* Wm2 = (const float*)d_in[11];
    const float* bm2 = (const float*)d_in[12];
    const float* v   = (const float*)d_in[13];

    float* out      = (float*)d_out;
    float* out_mean = out;                                   // [1024,256]
    float* R        = out + (size_t)NB * N;                  // [1024,256,256]
    float* out_z    = R + (size_t)NB * N * N;                // [1024,256]

    float* wsf   = (float*)d_ws;
    float* ws_a  = wsf;                            // [1024,256] f32
    float* ws_tp = wsf + (size_t)NB * N;
    float* ws_s  = wsf + (size_t)2 * NB * N;
    unsigned short* Wb = (unsigned short*)(wsf + (size_t)3 * NB * N);  // 6x65536 bf16

    prep_kernel<<<384, 256, 0, stream>>>(Wd1, Wu1, Wm1, Wd2, Wu2, Wm2, Wb);

    mlp_fused256_kernel<<<NB / 4, 1024, 0, stream>>>(
        x, Wb, bd1, bu1, bm1, bd2, bu2, bm2, v,
        out_mean, out_z, ws_a, ws_tp, ws_s);

    r_kernel<<<NB * 4, 256, 0, stream>>>(ws_a, ws_tp, ws_s, R);
}

// Round 16
// 72.155 us; speedup vs baseline: 1.1730x; 1.1713x over previous
//
#include <hip/hip_runtime.h>
#include <hip/hip_bf16.h>
#include <math.h>

#define NB 1024
#define N 256
#define NBN (NB * N)
#define EPS 1e-6f
#define SQRT_EPS 1e-3f   // sqrt(1e-6)

typedef short bf16x8 __attribute__((ext_vector_type(8)));
typedef float f32x4  __attribute__((ext_vector_type(4)));

__device__ __forceinline__ float fast_rcp(float x) {
    return __builtin_amdgcn_rcpf(x);
}
__device__ __forceinline__ float sigmoidf(float x) {
    return fast_rcp(1.0f + __expf(-x));
}
__device__ __forceinline__ float fast_tanh(float x) {
    float ax = fabsf(x);
    float e  = __expf(2.0f * ax);
    float t  = 1.0f - 2.0f * fast_rcp(e + 1.0f);
    return copysignf(t, x);
}
__device__ __forceinline__ unsigned short to_bf16(float f) {
    __hip_bfloat16 h = __float2bfloat16(f);
    return *(unsigned short*)&h;
}
__device__ __forceinline__ bf16x8 cvt8(float4 f0, float4 f1) {
    bf16x8 a;
    a[0] = (short)to_bf16(f0.x); a[1] = (short)to_bf16(f0.y);
    a[2] = (short)to_bf16(f0.z); a[3] = (short)to_bf16(f0.w);
    a[4] = (short)to_bf16(f1.x); a[5] = (short)to_bf16(f1.y);
    a[6] = (short)to_bf16(f1.z); a[7] = (short)to_bf16(f1.w);
    return a;
}

// ---- layer 1: 256 blocks (64 row-tiles x 4 col-tiles) x 768 threads.
// 12 waves = (mlp 0..2) x (16-neuron subtile 0..3). Weights converted
// f32->bf16 in-flight (no prep kernel). No LDS -> multi-block/CU.
// mfma_f32_16x16x32_bf16 frags (verified R12-R15, absmax 0.031):
//   A/B: lane idx = lane&15, k = (lane>>4)*8 + e
//   C/D: col = lane&15 (neuron), row = (lane>>4)*4 + reg (batch row)
__global__ __launch_bounds__(768) void l1_kernel(
    const float* __restrict__ x,
    const float* __restrict__ Wd1, const float* __restrict__ Wu1,
    const float* __restrict__ Wm1,
    const float* __restrict__ bd1, const float* __restrict__ bu1,
    const float* __restrict__ bm1, unsigned short* __restrict__ h1g)
{
    const int tid = threadIdx.x;
    const int w   = tid >> 6;          // 0..11
    const int mlp = w >> 2;            // 0..2
    const int sub = w & 3;             // 0..3
    const int l   = tid & 63;
    const int ml  = l & 15;
    const int kg  = l >> 4;
    const int b0  = (blockIdx.x >> 2) * 16;
    const int n0  = (blockIdx.x & 3) * 64 + sub * 16;
    const int n   = n0 + ml;

    // A-frags from x rows (f32 -> bf16)
    bf16x8 af[8];
    {
        const float* xrow = x + (size_t)(b0 + ml) * N;
        #pragma unroll
        for (int kq = 0; kq < 8; ++kq) {
            float4 f0 = *(const float4*)(xrow + kq * 32 + kg * 8);
            float4 f1 = *(const float4*)(xrow + kq * 32 + kg * 8 + 4);
            af[kq] = cvt8(f0, f1);
        }
    }
    const float* Wl = (mlp == 0) ? Wd1 : (mlp == 1) ? Wu1 : Wm1;
    const float* wrow = Wl + (size_t)n * N;
    f32x4 acc = {0.f, 0.f, 0.f, 0.f};
    #pragma unroll
    for (int kq = 0; kq < 8; ++kq) {
        float4 f0 = *(const float4*)(wrow + kq * 32 + kg * 8);
        float4 f1 = *(const float4*)(wrow + kq * 32 + kg * 8 + 4);
        bf16x8 bf = cvt8(f0, f1);
        acc = __builtin_amdgcn_mfma_f32_16x16x32_bf16(af[kq], bf, acc, 0, 0, 0);
    }
    const float* bias = (mlp == 0) ? bd1 : (mlp == 1) ? bu1 : bm1;
    const float bb = bias[n];
    #pragma unroll
    for (int reg = 0; reg < 4; ++reg) {
        const int row = b0 + kg * 4 + reg;
        float val = acc[reg] + bb;
        float act = (mlp < 2) ? sigmoidf(val) : fast_tanh(val);
        h1g[(size_t)mlp * NBN + (size_t)row * N + n] = to_bf16(act);
    }
}

// ---- layer 2: same geometry; A from h1g (bf16 direct), W2 cvt in-flight;
// writes h2g f32 (d,u,m planes).
__global__ __launch_bounds__(768) void l2_kernel(
    const unsigned short* __restrict__ h1g,
    const float* __restrict__ Wd2, const float* __restrict__ Wu2,
    const float* __restrict__ Wm2,
    const float* __restrict__ bd2, const float* __restrict__ bu2,
    const float* __restrict__ bm2, float* __restrict__ h2g)
{
    const int tid = threadIdx.x;
    const int w   = tid >> 6;
    const int mlp = w >> 2;
    const int sub = w & 3;
    const int l   = tid & 63;
    const int ml  = l & 15;
    const int kg  = l >> 4;
    const int b0  = (blockIdx.x >> 2) * 16;
    const int n0  = (blockIdx.x & 3) * 64 + sub * 16;
    const int n   = n0 + ml;

    bf16x8 af[8];
    {
        const unsigned short* arow = h1g + (size_t)mlp * NBN + (size_t)(b0 + ml) * N;
        #pragma unroll
        for (int kq = 0; kq < 8; ++kq)
            af[kq] = *(const bf16x8*)(arow + kq * 32 + kg * 8);
    }
    const float* Wl = (mlp == 0) ? Wd2 : (mlp == 1) ? Wu2 : Wm2;
    const float* wrow = Wl + (size_t)n * N;
    f32x4 acc = {0.f, 0.f, 0.f, 0.f};
    #pragma unroll
    for (int kq = 0; kq < 8; ++kq) {
        float4 f0 = *(const float4*)(wrow + kq * 32 + kg * 8);
        float4 f1 = *(const float4*)(wrow + kq * 32 + kg * 8 + 4);
        bf16x8 bf = cvt8(f0, f1);
        acc = __builtin_amdgcn_mfma_f32_16x16x32_bf16(af[kq], bf, acc, 0, 0, 0);
    }
    const float* bias = (mlp == 0) ? bd2 : (mlp == 1) ? bu2 : bm2;
    const float bb = bias[n];
    #pragma unroll
    for (int reg = 0; reg < 4; ++reg) {
        const int row = b0 + kg * 4 + reg;
        float val = acc[reg] + bb;
        float act = (mlp < 2) ? sigmoidf(val) : fast_tanh(val);
        h2g[(size_t)mlp * NBN + (size_t)row * N + n] = act;
    }
}

// ---- R writer with fused epilogue: 4096 blocks x 256 thr (R4 store
// structure, at write roofline). Each block recomputes row-b reductions
// from h2g (4x redundant, hides under store drain); chunk-0 writes mean/z.
__global__ __launch_bounds__(256) void r_epi_kernel(
    const float* __restrict__ h2g, const float* __restrict__ v,
    float* __restrict__ out_mean, float* __restrict__ out_z,
    float* __restrict__ R)
{
    __shared__ float s_lds[N];
    __shared__ float a_lds[64];
    __shared__ float tp_lds[64];
    __shared__ float red1[4][3];
    __shared__ float red2[4];

    const int tid   = threadIdx.x;
    const int b     = blockIdx.x >> 2;
    const int chunk = blockIdx.x & 3;
    const int ibase = chunk * 64;
    const int lane  = tid & 63;
    const int wv    = tid >> 6;

    // ---- epilogue recompute for row b (thread = column) ----
    const float d_ = h2g[(size_t)0 * NBN + (size_t)b * N + tid];
    const float u_ = h2g[(size_t)1 * NBN + (size_t)b * N + tid];
    const float m_ = h2g[(size_t)2 * NBN + (size_t)b * N + tid];
    const float vv = v[(size_t)b * N + tid];
    const float inv_d = fast_rcp(d_);

    float s0 = u_, s1 = u_ * u_ * inv_d, s2 = vv;
    #pragma unroll
    for (int off = 32; off > 0; off >>= 1) {
        s0 += __shfl_down(s0, off, 64);
        s1 += __shfl_down(s1, off, 64);
        s2 += __shfl_down(s2, off, 64);
    }
    if (lane == 0) { red1[wv][0] = s0; red1[wv][1] = s1; red1[wv][2] = s2; }
    __syncthreads();
    const float Su = red1[0][0] + red1[1][0] + red1[2][0] + red1[3][0];
    const float qs = red1[0][1] + red1[1][1] + red1[2][1] + red1[3][1];
    const float Sv = red1[0][2] + red1[1][2] + red1[2][2] + red1[3][2];
    const float utDu  = qs + EPS * Su * Su;
    const float sqeta = rsqrtf(1.0f + utDu);
    const float right = (1.0f - sqeta) / utDu;
    const float a  = sqrtf(inv_d + EPS);
    const float s  = u_ * a + SQRT_EPS * (Su - u_);
    const float tp = right * (u_ * inv_d + EPS * Su);

    float sv = s * vv;
    #pragma unroll
    for (int off = 32; off > 0; off >>= 1)
        sv += __shfl_down(sv, off, 64);
    if (lane == 0) red2[wv] = sv;

    // stage s (all cols) and a/tp (this chunk's rows) into LDS
    s_lds[tid] = s;
    if (tid >= ibase && tid < ibase + 64) {
        a_lds[tid - ibase]  = a;
        tp_lds[tid - ibase] = tp;
    }
    __syncthreads();
    sv = red2[0] + red2[1] + red2[2] + red2[3];

    if (chunk == 0) {
        const size_t idx = (size_t)b * N + tid;
        out_mean[idx] = m_;
        out_z[idx]    = SQRT_EPS * Sv + (a - SQRT_EPS) * vv - tp * sv + m_;
    }

    // ---- R store loop (R4-exact structure) ----
    const int j4 = tid & 63;
    const int il = tid >> 6;
    const float4 svec = ((const float4*)s_lds)[j4];
    float4* Rb = (float4*)(R + (size_t)b * N * N);
    const int jb = j4 * 4;

    #pragma unroll
    for (int it = 0; it < 16; ++it) {
        const int i_loc = it * 4 + il;
        const int i     = ibase + i_loc;
        const float ai  = a_lds[i_loc];
        const float ti  = tp_lds[i_loc];
        float4 o;
        o.x = SQRT_EPS - ti * svec.x;
        o.y = SQRT_EPS - ti * svec.y;
        o.z = SQRT_EPS - ti * svec.z;
        o.w = SQRT_EPS - ti * svec.w;
        if (i >= jb && i < jb + 4) {
            const float add = ai - SQRT_EPS;
            if      (i == jb)     o.x += add;
            else if (i == jb + 1) o.y += add;
            else if (i == jb + 2) o.z += add;
            else                  o.w += add;
        }
        Rb[(size_t)i * 64 + j4] = o;
    }
}

extern "C" void kernel_launch(void* const* d_in, const int* in_sizes, int n_in,
                              void* d_out, int out_size, void* d_ws, size_t ws_size,
                              hipStream_t stream) {
    const float* x   = (const float*)d_in[0];
    const float* Wd1 = (const float*)d_in[1];
    const float* bd1 = (const float*)d_in[2];
    const float* Wd2 = (const float*)d_in[3];
    const float* bd2 = (const float*)d_in[4];
    const float* Wu1 = (const float*)d_in[5];
    const float* bu1 = (const float*)d_in[6];
    const float* Wu2 = (const float*)d_in[7];
    const float* bu2 = (const float*)d_in[8];
    const float* Wm1 = (const float*)d_in[9];
    const float* bm1 = (const float*)d_in[10];
    const float* Wm2 = (const float*)d_in[11];
    const float* bm2 = (const float*)d_in[12];
    const float* v   = (const float*)d_in[13];

    float* out      = (float*)d_out;
    float* out_mean = out;                                   // [1024,256]
    float* R        = out + (size_t)NB * N;                  // [1024,256,256]
    float* out_z    = R + (size_t)NB * N * N;                // [1024,256]

    unsigned short* h1g = (unsigned short*)d_ws;             // 3x1024x256 bf16
    float* h2g = (float*)(h1g + (size_t)3 * NBN);            // 3x1024x256 f32

    l1_kernel<<<256, 768, 0, stream>>>(x, Wd1, Wu1, Wm1, bd1, bu1, bm1, h1g);
    l2_kernel<<<256, 768, 0, stream>>>(h1g, Wd2, Wu2, Wm2, bd2, bu2, bm2, h2g);
    r_epi_kernel<<<NB * 4, 256, 0, stream>>>(h2g, v, out_mean, out_z, R);
}